// Round 1
// baseline (317.586 us; speedup 1.0000x reference)
//
#include <hip/hip_runtime.h>

// Problem constants
#define S_LEN 256
#define B_SZ  128
#define D_1   1024
#define H_SZ  1024
#define M_ROWS (S_LEN * B_SZ)          // 32768
#define K_SEQ  1024

typedef __attribute__((ext_vector_type(8))) short bf16x8;
typedef __attribute__((ext_vector_type(4))) float f32x4;

__device__ __forceinline__ unsigned short f2bf(float x) {
    unsigned u = __float_as_uint(x);
    unsigned r = (u + 0x7fffu + ((u >> 16) & 1u)) >> 16;   // RNE
    return (unsigned short)r;
}

__device__ __forceinline__ void gl_lds16(const void* g, void* l) {
    __builtin_amdgcn_global_load_lds(
        (const __attribute__((address_space(1))) unsigned int*)g,
        (__attribute__((address_space(3))) unsigned int*)l,
        16, 0, 0);
}

// ---------------- Pass 1: seq f32 -> bf16 ----------------
__global__ __launch_bounds__(256) void convert_seq(const float* __restrict__ in,
                                                   unsigned short* __restrict__ out,
                                                   long n4) {
    long i = (long)blockIdx.x * blockDim.x + threadIdx.x;
    long stride = (long)gridDim.x * blockDim.x;
    for (; i < n4; i += stride) {
        float4 v = ((const float4*)in)[i];
        ushort4 o;
        o.x = f2bf(v.x); o.y = f2bf(v.y); o.z = f2bf(v.z); o.w = f2bf(v.w);
        ((ushort4*)out)[i] = o;
    }
}

// ---------------- Pass 2: f1,f2 f32 -> bf16 (layer-major) ----------------
__global__ __launch_bounds__(256) void convert_f(const float* __restrict__ f1,
                                                 const float* __restrict__ f2,
                                                 unsigned short* __restrict__ out) {
    int g = blockIdx.x * 256 + threadIdx.x;            // 0..65535 float4 groups
    float4 v = (g < 32768) ? ((const float4*)f1)[g] : ((const float4*)f2)[g - 32768];
    ushort4 o;
    o.x = f2bf(v.x); o.y = f2bf(v.y); o.z = f2bf(v.z); o.w = f2bf(v.w);
    ((ushort4*)out)[g] = o;
}

// ---------------- Pass 3: W [2048][1024] f32 -> Wt [2][1024][2048] bf16 ----------------
__global__ __launch_bounds__(256) void transpose_w(const float* __restrict__ W11,
                                                   const float* __restrict__ W12,
                                                   unsigned short* __restrict__ Wt) {
    const int nt = blockIdx.x, kt = blockIdx.y, layer = blockIdx.z;
    const float* W = layer ? W12 : W11;
    __shared__ float T[64][65];
    const int c = threadIdx.x & 63, r4 = threadIdx.x >> 6;
    const int k0 = kt * 64, n0 = nt * 64;
    #pragma unroll
    for (int p = 0; p < 16; ++p) {
        int r = p * 4 + r4;
        T[r][c] = W[(size_t)(k0 + r) * 1024 + n0 + c];
    }
    __syncthreads();
    unsigned short* Wl = Wt + (size_t)layer * 1024 * 2048;
    #pragma unroll
    for (int p = 0; p < 16; ++p) {
        int n = p * 4 + r4;
        Wl[(size_t)(n0 + n) * 2048 + k0 + c] = f2bf(T[c][n]);
    }
}

// ---------------- Pass 4: c[layer][b][h] = f@W[1024:] + bias  (MFMA 128x128 tile) ----------------
__global__ __launch_bounds__(256) void c_precompute(const unsigned short* __restrict__ fbf, // [2][128][1024]
                                                    const unsigned short* __restrict__ Wt,  // [2][1024][2048]
                                                    const float* __restrict__ b11,
                                                    const float* __restrict__ b12,
                                                    float* __restrict__ cbuf) {            // [2][128][1024]
    __shared__ char smem[32768];
    unsigned short* ldsA = (unsigned short*)smem;            // [128][64]
    unsigned short* ldsB = (unsigned short*)(smem + 16384);  // [128][64]
    const int n0 = blockIdx.x * 128;
    const int layer = blockIdx.y;
    const int tid = threadIdx.x;
    const int w = tid >> 6, l = tid & 63;
    const int wm = w >> 1, wn = w & 1;
    const int lr = l & 15, lg = l >> 4;
    const unsigned short* Af = fbf + (size_t)layer * 128 * 1024;
    const unsigned short* Wl = Wt + (size_t)layer * 1024 * 2048;
    const float* bias = layer ? b12 : b11;

    f32x4 acc[4][4];
    #pragma unroll
    for (int i = 0; i < 4; ++i)
        #pragma unroll
        for (int j = 0; j < 4; ++j)
            #pragma unroll
            for (int e = 0; e < 4; ++e) acc[i][j][e] = 0.f;

    for (int kk = 0; kk < 1024; kk += 64) {
        __syncthreads();
        #pragma unroll
        for (int c = 0; c < 4; ++c) {
            int o = w * 4096 + c * 1024;
            int ob = o + l * 16;
            int row = ob >> 7, kb = ob & 127;
            gl_lds16((const char*)Af + ((size_t)row * 1024 + kk) * 2 + kb, (char*)ldsA + o);
            gl_lds16((const char*)Wl + ((size_t)(n0 + row) * 2048 + 1024 + kk) * 2 + kb, (char*)ldsB + o);
        }
        __syncthreads();
        #pragma unroll
        for (int ks = 0; ks < 2; ++ks) {
            bf16x8 av[4], bv[4];
            #pragma unroll
            for (int i = 0; i < 4; ++i) {
                av[i] = *(const bf16x8*)(ldsA + (wm * 64 + i * 16 + lr) * 64 + ks * 32 + lg * 8);
                bv[i] = *(const bf16x8*)(ldsB + (wn * 64 + i * 16 + lr) * 64 + ks * 32 + lg * 8);
            }
            #pragma unroll
            for (int i = 0; i < 4; ++i)
                #pragma unroll
                for (int j = 0; j < 4; ++j)
                    acc[i][j] = __builtin_amdgcn_mfma_f32_16x16x32_bf16(av[i], bv[j], acc[i][j], 0, 0, 0);
        }
    }
    float* cl = cbuf + (size_t)layer * 128 * 1024;
    #pragma unroll
    for (int i = 0; i < 4; ++i)
        #pragma unroll
        for (int j = 0; j < 4; ++j)
            #pragma unroll
            for (int q = 0; q < 4; ++q) {
                int rr = wm * 64 + i * 16 + lg * 4 + q;
                int hc = n0 + wn * 64 + j * 16 + lr;
                cl[(size_t)rr * 1024 + hc] = acc[i][j][q] + bias[hc];
            }
}

// ---------------- Pass 5: main fused GEMM + tanh + dot ----------------
// block = one s-slice (128 rows = all b) x one layer; loops 8 N-tiles of 128
__global__ __launch_bounds__(256) void fused_main(const unsigned short* __restrict__ Abf, // [32768][1024]
                                                  const unsigned short* __restrict__ Wt,  // [2][1024][2048]
                                                  const float* __restrict__ cbuf,         // [2][128][1024]
                                                  const float* __restrict__ W21,
                                                  const float* __restrict__ W22,
                                                  float* __restrict__ sbuf) {             // [2][32768]
    __shared__ char smem[32768];
    unsigned short* ldsA = (unsigned short*)smem;            // [128][64]
    unsigned short* ldsB = (unsigned short*)(smem + 16384);  // [128][64]
    const int bx = blockIdx.x;       // s index / M-tile
    const int layer = blockIdx.y;
    const int tid = threadIdx.x;
    const int w = tid >> 6, l = tid & 63;
    const int wm = w >> 1, wn = w & 1;
    const int lr = l & 15, lg = l >> 4;
    const size_t Abase = (size_t)bx * 128 * 1024;
    const unsigned short* Wl = Wt + (size_t)layer * 1024 * 2048;
    const float* cl = cbuf + (size_t)layer * 128 * 1024;
    const float* Wsel = layer ? W22 : W21;

    float psum[4][4];
    #pragma unroll
    for (int i = 0; i < 4; ++i)
        #pragma unroll
        for (int q = 0; q < 4; ++q) psum[i][q] = 0.f;

    for (int nt = 0; nt < 8; ++nt) {
        const int n0 = nt * 128;
        f32x4 acc[4][4];
        #pragma unroll
        for (int i = 0; i < 4; ++i)
            #pragma unroll
            for (int j = 0; j < 4; ++j)
                #pragma unroll
                for (int e = 0; e < 4; ++e) acc[i][j][e] = 0.f;

        for (int kk = 0; kk < 1024; kk += 64) {
            __syncthreads();
            #pragma unroll
            for (int c = 0; c < 4; ++c) {
                int o = w * 4096 + c * 1024;
                int ob = o + l * 16;
                int row = ob >> 7, kb = ob & 127;
                gl_lds16((const char*)Abf + (Abase + (size_t)row * 1024 + kk) * 2 + kb, (char*)ldsA + o);
                gl_lds16((const char*)Wl + ((size_t)(n0 + row) * 2048 + kk) * 2 + kb, (char*)ldsB + o);
            }
            __syncthreads();
            #pragma unroll
            for (int ks = 0; ks < 2; ++ks) {
                bf16x8 av[4], bv[4];
                #pragma unroll
                for (int i = 0; i < 4; ++i) {
                    av[i] = *(const bf16x8*)(ldsA + (wm * 64 + i * 16 + lr) * 64 + ks * 32 + lg * 8);
                    bv[i] = *(const bf16x8*)(ldsB + (wn * 64 + i * 16 + lr) * 64 + ks * 32 + lg * 8);
                }
                #pragma unroll
                for (int i = 0; i < 4; ++i)
                    #pragma unroll
                    for (int j = 0; j < 4; ++j)
                        acc[i][j] = __builtin_amdgcn_mfma_f32_16x16x32_bf16(av[i], bv[j], acc[i][j], 0, 0, 0);
            }
        }
        // epilogue: z = acc + c, h = tanh(z), partial dot with W21/W22
        float wsel[4];
        #pragma unroll
        for (int j = 0; j < 4; ++j) wsel[j] = Wsel[n0 + wn * 64 + j * 16 + lr];
        #pragma unroll
        for (int i = 0; i < 4; ++i)
            #pragma unroll
            for (int q = 0; q < 4; ++q) {
                int rr = wm * 64 + i * 16 + lg * 4 + q;
                float p = 0.f;
                #pragma unroll
                for (int j = 0; j < 4; ++j) {
                    int hc = n0 + wn * 64 + j * 16 + lr;
                    float z = acc[i][j][q] + cl[(size_t)rr * 1024 + hc];
                    float e = __expf(2.f * z);
                    float hh = 1.f - 2.f / (e + 1.f);   // tanh(z)
                    p += hh * wsel[j];
                }
                psum[i][q] += p;
            }
    }
    // reduce over the 16 lanes (columns) in each group
    #pragma unroll
    for (int i = 0; i < 4; ++i)
        #pragma unroll
        for (int q = 0; q < 4; ++q) {
            float v = psum[i][q];
            v += __shfl_xor(v, 1);
            v += __shfl_xor(v, 2);
            v += __shfl_xor(v, 4);
            v += __shfl_xor(v, 8);
            psum[i][q] = v;
        }
    __syncthreads();
    float* srow = (float*)smem;   // [128][2]
    if (lr == 0) {
        #pragma unroll
        for (int i = 0; i < 4; ++i)
            #pragma unroll
            for (int q = 0; q < 4; ++q) {
                int rr = wm * 64 + i * 16 + lg * 4 + q;
                srow[rr * 2 + wn] = psum[i][q];
            }
    }
    __syncthreads();
    if (tid < 128)
        sbuf[(size_t)layer * M_ROWS + (size_t)bx * 128 + tid] = srow[tid * 2] + srow[tid * 2 + 1];
}

// ---------------- Pass 6: softmax over s -> coef; also zero d_out ----------------
__device__ __forceinline__ float block_max(float v, float* lds) {
    #pragma unroll
    for (int m = 32; m; m >>= 1) v = fmaxf(v, __shfl_xor(v, m));
    if ((threadIdx.x & 63) == 0) lds[threadIdx.x >> 6] = v;
    __syncthreads();
    v = fmaxf(fmaxf(lds[0], lds[1]), fmaxf(lds[2], lds[3]));
    __syncthreads();
    return v;
}
__device__ __forceinline__ float block_sum(float v, float* lds) {
    #pragma unroll
    for (int m = 32; m; m >>= 1) v += __shfl_xor(v, m);
    if ((threadIdx.x & 63) == 0) lds[threadIdx.x >> 6] = v;
    __syncthreads();
    v = lds[0] + lds[1] + lds[2] + lds[3];
    __syncthreads();
    return v;
}

__global__ __launch_bounds__(256) void coef_kernel(const float* __restrict__ sbuf,
                                                   float* __restrict__ coef,
                                                   float* __restrict__ out) {
    __shared__ float lds[4];
    const int b = blockIdx.x, s = threadIdx.x;
    float v1 = sbuf[(size_t)s * 128 + b];
    float v2 = sbuf[(size_t)M_ROWS + (size_t)s * 128 + b];
    float m1 = block_max(v1, lds);
    float e1 = expf(v1 - m1);
    float S1 = block_sum(e1, lds);
    float m2 = block_max(v2, lds);
    float e2 = expf(v2 - m2);
    float S2 = block_sum(e2, lds);
    coef[(size_t)s * 128 + b] = (e1 / S1 + e2 / S2) * (0.5f / (float)S_LEN);
    // zero d_out: block b owns row b (1024 floats = 256 float4)
    float4 z4; z4.x = z4.y = z4.z = z4.w = 0.f;
    ((float4*)out)[(size_t)b * 256 + s] = z4;
}

// ---------------- Pass 7: out[b][d] = sum_s coef[s][b] * seq[s][b][d] ----------------
__global__ __launch_bounds__(256) void final_kernel(const float* __restrict__ seq,
                                                    const float* __restrict__ coef,
                                                    float* __restrict__ out) {
    const int b = blockIdx.x, q = blockIdx.y;
    const int d0 = threadIdx.x * 4;
    float4 a; a.x = a.y = a.z = a.w = 0.f;
    for (int si = 0; si < 64; ++si) {
        int s = q * 64 + si;
        float cf = coef[(size_t)s * 128 + b];
        float4 v = *(const float4*)(seq + ((size_t)(s * 128 + b) * 1024 + d0));
        a.x += cf * v.x; a.y += cf * v.y; a.z += cf * v.z; a.w += cf * v.w;
    }
    float* o = out + (size_t)b * 1024 + d0;
    atomicAdd(o + 0, a.x);
    atomicAdd(o + 1, a.y);
    atomicAdd(o + 2, a.z);
    atomicAdd(o + 3, a.w);
}

extern "C" void kernel_launch(void* const* d_in, const int* in_sizes, int n_in,
                              void* d_out, int out_size, void* d_ws, size_t ws_size,
                              hipStream_t stream) {
    const float* feature1 = (const float*)d_in[0];   // [128,1024]
    const float* feature2 = (const float*)d_in[1];   // [128,1024]
    const float* seq      = (const float*)d_in[2];   // [256,128,1024]
    const float* W11      = (const float*)d_in[3];   // [2048,1024]
    const float* b11      = (const float*)d_in[4];
    const float* W12      = (const float*)d_in[5];
    const float* b12      = (const float*)d_in[6];
    const float* W21      = (const float*)d_in[7];   // [1024,1]
    const float* W22      = (const float*)d_in[9];
    float* out = (float*)d_out;

    char* ws = (char*)d_ws;
    unsigned short* Abf  = (unsigned short*)(ws + 0);                  // 67108864 B
    unsigned short* Wt   = (unsigned short*)(ws + 67108864);           //  8388608 B
    unsigned short* fbf  = (unsigned short*)(ws + 75497472);           //   524288 B
    float*          cbuf = (float*)(ws + 76021760);                    //  1048576 B
    float*          sbuf = (float*)(ws + 77070336);                    //   262144 B
    float*          coef = (float*)(ws + 77332480);                    //   131072 B

    convert_seq<<<2048, 256, 0, stream>>>(seq, Abf, (long)M_ROWS * 1024 / 4);
    convert_f<<<256, 256, 0, stream>>>(feature1, feature2, fbf);
    transpose_w<<<dim3(16, 32, 2), 256, 0, stream>>>(W11, W12, Wt);
    c_precompute<<<dim3(8, 2), 256, 0, stream>>>(fbf, Wt, b11, b12, cbuf);
    fused_main<<<dim3(256, 2), 256, 0, stream>>>(Abf, Wt, cbuf, W21, W22, sbuf);
    coef_kernel<<<128, 256, 0, stream>>>(sbuf, coef, out);
    final_kernel<<<dim3(128, 4), 256, 0, stream>>>(seq, coef, out);
}